// Round 5
// baseline (222.154 us; speedup 1.0000x reference)
//
#include <hip/hip_runtime.h>
#include <hip/hip_bf16.h>
#include <math.h>

typedef unsigned short ushort_t;
typedef __attribute__((ext_vector_type(8))) short bf16x8;
typedef __attribute__((ext_vector_type(4))) float f32x4;

constexpr int BATCH   = 4;
constexpr int LEN_IN  = 5440;
constexpr int LEN_Q   = 5440;
constexpr int M_TOT   = BATCH * LEN_Q;   // 21760 rows = 1360 m-tiles of 16

__device__ __forceinline__ ushort_t bfbits(float x) {
    __hip_bfloat16 h = __float2bfloat16(x);
    ushort_t u; __builtin_memcpy(&u, &h, 2); return u;
}
__device__ __forceinline__ unsigned pk2(float a, float b) {
    return (unsigned)bfbits(a) | ((unsigned)bfbits(b) << 16);
}

// ======================= weight pack / transpose (tiny) =======================
// blocks [0,32)   : W_val  [256k,256n] -> wvT  [256n][256k] bf16
// blocks [32,64)  : W_out  -> woutT
// blocks [64,112) : W_off|W_attn -> woaT [384n][256k] bf16
// block  112      : bias concat (b_off | b_attn)
__global__ __launch_bounds__(256) void pack_w(
    const float* __restrict__ Wv, const float* __restrict__ Wo,
    const float* __restrict__ Wa, const float* __restrict__ Wout,
    const float* __restrict__ b_off, const float* __restrict__ b_attn,
    ushort_t* __restrict__ wvT, ushort_t* __restrict__ woaT,
    ushort_t* __restrict__ woutT, float* __restrict__ bias_oa)
{
    const int blk = blockIdx.x, tid = threadIdx.x;
    if (blk < 64) {
        const float* src = (blk < 32) ? Wv : Wout;
        ushort_t*    dst = (blk < 32) ? wvT : woutT;
        const int base = (blk & 31) * 2048;
#pragma unroll
        for (int i = 0; i < 8; i++) {
            const int idx = base + i * 256 + tid;
            const int k = idx >> 8, n = idx & 255;
            dst[n * 256 + k] = bfbits(src[idx]);
        }
    } else if (blk < 112) {
        const int base = (blk - 64) * 2048;
#pragma unroll
        for (int i = 0; i < 8; i++) {
            const int idx = base + i * 256 + tid;   // < 98304
            const int k = idx / 384, j = idx - k * 384;
            const float v = (j < 256) ? Wo[k * 256 + j] : Wa[k * 128 + (j - 256)];
            woaT[j * 256 + k] = bfbits(v);
        }
    } else {
        bias_oa[tid] = b_off[tid];
        if (tid < 128) bias_oa[256 + tid] = b_attn[tid];
    }
}

// ======================= wave-autonomous weight-stationary GEMM ============
// One wave (64-thread block) owns a 64-col n-strip of BT [N,256] held in
// registers (4 n-tiles x 8 k-frags = 128 VGPR) and streams MC=8 m-tiles of A
// directly from global into MFMA A-frag layout. No LDS, no barriers.
// A frag: lane -> A[row0 + (lane&15)][ (lane>>4)*8 + j ]
// C/D:    lane -> C[row0 + (lane>>4)*4 + r][ n0 + nt*16 + (lane&15) ]
constexpr int MC = 8;   // m-tiles per wave job; 1360 = 170 * 8

template <bool A_F32, bool OUT_BF16>
__device__ __forceinline__ void gemm_wave(
    const void* __restrict__ Ap, const ushort_t* __restrict__ BT,
    const float* __restrict__ bias, void* __restrict__ Cp, int N,
    int n0, int row_base)
{
    const int lane  = threadIdx.x & 63;
    const int row16 = lane & 15;
    const int kg8   = (lane >> 4) * 8;
    const int rb4   = (lane >> 4) * 4;

    // ---- load B frags (weight-stationary) ----
    bf16x8 Bf[4][8];
#pragma unroll
    for (int nt = 0; nt < 4; nt++)
#pragma unroll
        for (int kt = 0; kt < 8; kt++)
            Bf[nt][kt] = *(const bf16x8*)(BT + (size_t)(n0 + nt * 16 + row16) * 256
                                             + kt * 32 + kg8);
    float bv[4];
#pragma unroll
    for (int nt = 0; nt < 4; nt++) bv[nt] = bias[n0 + nt * 16 + row16];

    // ---- stream m-tiles ----
#pragma unroll 1
    for (int mt = 0; mt < MC; mt++) {
        const int row0 = row_base + mt * 16;
        bf16x8 af[8];
        if (A_F32) {
            const float* ap = (const float*)Ap + (size_t)(row0 + row16) * 256 + kg8;
#pragma unroll
            for (int kt = 0; kt < 8; kt++) {
                float4 f0 = *(const float4*)(ap + kt * 32);
                float4 f1 = *(const float4*)(ap + kt * 32 + 4);
                uint4 u;
                u.x = pk2(f0.x, f0.y); u.y = pk2(f0.z, f0.w);
                u.z = pk2(f1.x, f1.y); u.w = pk2(f1.z, f1.w);
                __builtin_memcpy(&af[kt], &u, 16);
            }
        } else {
            const ushort_t* ap = (const ushort_t*)Ap + (size_t)(row0 + row16) * 256 + kg8;
#pragma unroll
            for (int kt = 0; kt < 8; kt++)
                af[kt] = *(const bf16x8*)(ap + kt * 32);
        }

        f32x4 acc[4] = {};
#pragma unroll
        for (int kt = 0; kt < 8; kt++)
#pragma unroll
            for (int nt = 0; nt < 4; nt++)
                acc[nt] = __builtin_amdgcn_mfma_f32_16x16x32_bf16(
                    af[kt], Bf[nt][kt], acc[nt], 0, 0, 0);

#pragma unroll
        for (int nt = 0; nt < 4; nt++) {
            const int cc = n0 + nt * 16 + row16;
#pragma unroll
            for (int r = 0; r < 4; r++) {
                const float v = acc[nt][r] + bv[nt];
                const size_t ci = (size_t)(row0 + rb4 + r) * N + cc;
                if (OUT_BF16) ((ushort_t*)Cp)[ci] = bfbits(v);
                else          ((float*)Cp)[ci] = v;
            }
        }
    }
}

// jobs [0,680)    : value  = in_flat(f32)[M,256] @ wvT  -> bf16, N=256 (4 strips)
// jobs [680,1700) : offattn= query(f32)[M,256]   @ woaT -> f32,  N=384 (6 strips)
__global__ __launch_bounds__(64, 2) void gemm_vo(
    const float* __restrict__ inflat, const ushort_t* __restrict__ wvT,
    const float* __restrict__ b_val, ushort_t* __restrict__ value_bf,
    const float* __restrict__ query, const ushort_t* __restrict__ woaT,
    const float* __restrict__ bias_oa, float* __restrict__ offattn)
{
    int j = blockIdx.x;
    if (j < 680) {
        const int s = j & 3, chunk = j >> 2;
        gemm_wave<true, true>(inflat, wvT, b_val, value_bf, 256,
                              s * 64, chunk * (MC * 16));
    } else {
        j -= 680;
        const int s = j % 6, chunk = j / 6;
        gemm_wave<true, false>(query, woaT, bias_oa, offattn, 384,
                               s * 64, chunk * (MC * 16));
    }
}

__global__ __launch_bounds__(64, 2) void gemm_out(
    const ushort_t* __restrict__ mid_bf, const ushort_t* __restrict__ woutT,
    const float* __restrict__ b_out, float* __restrict__ out)
{
    const int s = blockIdx.x & 3, chunk = blockIdx.x >> 2;
    gemm_wave<false, false>(mid_bf, woutT, b_out, out, 256,
                            s * 64, chunk * (MC * 16));
}

// ======================= softmax + bilinear sampling =======================
// (round-3 version: 52 VGPR, 8 waves/SIMD — TLP beats in-thread pipelining)
// 256 thr = 8 queries x (8 heads x 4 lanes); lane owns 8 bf16 channels (16 B).
__device__ __forceinline__ void acc8(float* acc, uint4 v, float w) {
    const unsigned* p = &v.x;
#pragma unroll
    for (int d = 0; d < 4; d++) {
        const unsigned u = p[d];
        const float lo = __uint_as_float(u << 16);
        const float hi = __uint_as_float(u & 0xFFFF0000u);
        acc[2 * d]     = fmaf(w, lo, acc[2 * d]);
        acc[2 * d + 1] = fmaf(w, hi, acc[2 * d + 1]);
    }
}

__global__ __launch_bounds__(256) void msda_sample_bf16(
    const ushort_t* __restrict__ value, const float* __restrict__ refp,
    const float* __restrict__ offattn, ushort_t* __restrict__ mid)
{
    constexpr int LVL_H[4]  = {64, 32, 16, 8};
    constexpr int LVL_W[4]  = {64, 32, 16, 8};
    constexpr int LVL_ST[4] = {0, 4096, 5120, 5376};

    const int tid  = threadIdx.x;
    const int bq   = blockIdx.x * 8 + (tid >> 5);
    const int b    = bq / LEN_Q;
    const int t32  = tid & 31;
    const int head = t32 >> 2;
    const int c8   = (t32 & 3) * 8;

    const float* base = offattn + (size_t)bq * 384;
    const float* lp = base + 256 + head * 16;
    float4 l0 = ((const float4*)lp)[0];
    float4 l1 = ((const float4*)lp)[1];
    float4 l2 = ((const float4*)lp)[2];
    float4 l3 = ((const float4*)lp)[3];
    float lg[16] = {l0.x, l0.y, l0.z, l0.w, l1.x, l1.y, l1.z, l1.w,
                    l2.x, l2.y, l2.z, l2.w, l3.x, l3.y, l3.z, l3.w};
    float mx = lg[0];
#pragma unroll
    for (int j = 1; j < 16; j++) mx = fmaxf(mx, lg[j]);

    const float* op = base + head * 32;
    float4 ov[8];
#pragma unroll
    for (int j = 0; j < 8; j++) ov[j] = ((const float4*)op)[j];
    const float* rp = refp + (size_t)bq * 8;
    float4 r0 = ((const float4*)rp)[0];
    float4 r1 = ((const float4*)rp)[1];
    const float rx[4] = {r0.x, r0.z, r1.x, r1.z};
    const float ry[4] = {r0.y, r0.w, r1.y, r1.w};

    const ushort_t* vbase = value + (size_t)b * LEN_IN * 256 + head * 32 + c8;

    float acc[8] = {};
    float esum = 0.f;

#pragma unroll
    for (int l = 0; l < 4; l++) {
        const int H = LVL_H[l], W = LVL_W[l], st = LVL_ST[l];
        const float fW = (float)W, fH = (float)H;
#pragma unroll
        for (int p = 0; p < 4; p++) {
            const float* o2 = &ov[l * 2].x;
            const float ox = o2[p * 2 + 0];
            const float oy = o2[p * 2 + 1];
            const float x = (rx[l] + ox / fW) * fW - 0.5f;
            const float y = (ry[l] + oy / fH) * fH - 0.5f;
            const float x0f = floorf(x), y0f = floorf(y);
            const float wx = x - x0f, wy = y - y0f;
            const int ix0 = (int)x0f, iy0 = (int)y0f;
            const int ix1 = ix0 + 1,  iy1 = iy0 + 1;
            const float vx0 = (ix0 >= 0 && ix0 < W) ? 1.f : 0.f;
            const float vx1 = (ix1 >= 0 && ix1 < W) ? 1.f : 0.f;
            const float vy0 = (iy0 >= 0 && iy0 < H) ? 1.f : 0.f;
            const float vy1 = (iy1 >= 0 && iy1 < H) ? 1.f : 0.f;
            const int cx0 = min(max(ix0, 0), W - 1);
            const int cx1 = min(max(ix1, 0), W - 1);
            const int cy0 = min(max(iy0, 0), H - 1);
            const int cy1 = min(max(iy1, 0), H - 1);
            const float hx0 = (1.f - wx) * vx0, hx1 = wx * vx1;
            const float hy0 = (1.f - wy) * vy0, hy1 = wy * vy1;

            const ushort_t* rp0 = vbase + (size_t)(st + cy0 * W) * 256;
            const ushort_t* rp1 = vbase + (size_t)(st + cy1 * W) * 256;
            uint4 v00 = *(const uint4*)(rp0 + (size_t)cx0 * 256);
            uint4 v01 = *(const uint4*)(rp0 + (size_t)cx1 * 256);
            uint4 v10 = *(const uint4*)(rp1 + (size_t)cx0 * 256);
            uint4 v11 = *(const uint4*)(rp1 + (size_t)cx1 * 256);

            const float e = __expf(lg[l * 4 + p] - mx);
            esum += e;
            acc8(acc, v00, e * hx0 * hy0);
            acc8(acc, v01, e * hx1 * hy0);
            acc8(acc, v10, e * hx0 * hy1);
            acc8(acc, v11, e * hx1 * hy1);
        }
    }

    const float inv = 1.f / esum;
    uint4 o;
    o.x = pk2(acc[0] * inv, acc[1] * inv);
    o.y = pk2(acc[2] * inv, acc[3] * inv);
    o.z = pk2(acc[4] * inv, acc[5] * inv);
    o.w = pk2(acc[6] * inv, acc[7] * inv);
    *(uint4*)(mid + (size_t)bq * 256 + head * 32 + c8) = o;
}

// ======================= launch =======================
extern "C" void kernel_launch(void* const* d_in, const int* in_sizes, int n_in,
                              void* d_out, int out_size, void* d_ws, size_t ws_size,
                              hipStream_t stream)
{
    const float* query  = (const float*)d_in[0];
    const float* refp   = (const float*)d_in[1];
    const float* inflat = (const float*)d_in[2];
    const float* W_val  = (const float*)d_in[5];
    const float* b_val  = (const float*)d_in[6];
    const float* W_off  = (const float*)d_in[7];
    const float* b_off  = (const float*)d_in[8];
    const float* W_attn = (const float*)d_in[9];
    const float* b_attn = (const float*)d_in[10];
    const float* W_out  = (const float*)d_in[11];
    const float* b_out  = (const float*)d_in[12];
    float* out = (float*)d_out;

    char* ws = (char*)d_ws;
    ushort_t* value_bf = (ushort_t*)ws;                    // 11,141,120
    ushort_t* mid_bf   = (ushort_t*)(ws + 11141120);       // 11,141,120
    float*    offattn  = (float*)   (ws + 22282240);       // 33,423,360
    ushort_t* wvT      = (ushort_t*)(ws + 55705600);       // 131,072
    ushort_t* woutT    = (ushort_t*)(ws + 55836672);       // 131,072
    ushort_t* woaT     = (ushort_t*)(ws + 55967744);       // 196,608
    float*    bias_oa  = (float*)   (ws + 56164352);       // 1,536

    pack_w<<<dim3(113), dim3(256), 0, stream>>>(
        W_val, W_off, W_attn, W_out, b_off, b_attn, wvT, woaT, woutT, bias_oa);
    gemm_vo<<<dim3(1700), dim3(64), 0, stream>>>(
        inflat, wvT, b_val, value_bf, query, woaT, bias_oa, offattn);
    msda_sample_bf16<<<dim3(M_TOT / 8), dim3(256), 0, stream>>>(
        value_bf, refp, offattn, mid_bf);
    gemm_out<<<dim3(680), dim3(64), 0, stream>>>(
        mid_bf, woutT, b_out, out);
}